// Round 1
// baseline (94.471 us; speedup 1.0000x reference)
//
#include <hip/hip_runtime.h>
#include <math.h>

// OT disparity: banded unbalanced Sinkhorn.
// W=312 rows, C=360 cols, band of 48 finite entries per row (c = j+48-d).
// BIG_COST entries underflow to exactly 0 in every fp32 exp -> ignore them.

#define MAXD   48
#define WROWS  312
#define CCOLS  360
#define NITER  10
#define NT     384          // 6 waves
#define NWAVE  (NT / 64)

__device__ __forceinline__ void lse_comb(float& m, float& s, float m2, float s2) {
    float nm = fmaxf(m, m2);
    s = s * __expf(m - nm) + s2 * __expf(m2 - nm);
    m = nm;
}

// Block-wide logsumexp of x over active threads. Every thread returns the result.
__device__ __forceinline__ float block_lse(float x, bool active,
                                           float* red_m, float* red_s) {
    float m = active ? x : -3e38f;
    float s = active ? 1.0f : 0.0f;
    #pragma unroll
    for (int off = 32; off >= 1; off >>= 1) {
        float m2 = __shfl_xor(m, off);
        float s2 = __shfl_xor(s, off);
        lse_comb(m, s, m2, s2);
    }
    int wid = threadIdx.x >> 6;
    if ((threadIdx.x & 63) == 0) { red_m[wid] = m; red_s[wid] = s; }
    __syncthreads();
    float M = -3e38f, S = 0.0f;
    #pragma unroll
    for (int w = 0; w < NWAVE; ++w) lse_comb(M, S, red_m[w], red_s[w]);
    __syncthreads();   // scratch reusable afterwards
    return M + __logf(S);
}

__global__ __launch_bounds__(NT)
void ot_disp_kernel(const float* __restrict__ scores, float* __restrict__ out) {
    const int bid = blockIdx.x;      // 0..127  (= b*64 + h)
    const int tid = threadIdx.x;

    const float LOG_A  = -5.7430032f;   // -log(312)
    const float LOG_B  = -5.8861040f;   // -log(360)
    const float TAU    = 0.95f;
    const float KAPPA  = 0.025f;        // (1-tau)/2
    const float XI     = 0.025641026f;  // (1-tau)/(1+tau)
    const float RHO    = 19.0f;         // eps*tau/(1-tau)
    const float INVRHO = 1.0f / 19.0f;

    __shared__ float s_sc[MAXD * WROWS];   // scores s[d][j]
    __shared__ float s_f[WROWS];
    __shared__ float s_g[CCOLS];
    __shared__ float red_m[NWAVE], red_s[NWAVE];

    // ---- stage scores tile into LDS (coalesced) ----
    // scores layout (B,D,H,W): offset = ((b*48 + d)*64 + h)*312 + j
    const int b = bid >> 6, h = bid & 63;
    const float* src = scores + ((size_t)b * MAXD * 64 + h) * WROWS;
    for (int idx = tid; idx < MAXD * WROWS; idx += NT) {
        int d = idx / WROWS;
        int j = idx - d * WROWS;
        s_sc[idx] = src[(size_t)d * 64 * WROWS + j];
    }
    __syncthreads();

    // ---- init f:  f_j = -log_b - LSE_d(s[d][j]);  sminF = smin(f, log_a) ----
    float sminF;
    {
        float x = -3e38f;
        if (tid < WROWS) {
            float m = -3e38f;
            for (int d = 0; d < MAXD; ++d) m = fmaxf(m, s_sc[d * WROWS + tid]);
            float sum = 0.0f;
            for (int d = 0; d < MAXD; ++d) sum += __expf(s_sc[d * WROWS + tid] - m);
            float fj = -LOG_B - (m + __logf(sum));
            s_f[tid] = fj;
            x = -fj * INVRHO + LOG_A;
        }
        sminF = -RHO * block_lse(x, tid < WROWS, red_m, red_s);  // contains syncs
    }

    // ---- Sinkhorn iterations ----
    for (int it = 0; it < NITER; ++it) {
        // column pass: c = tid in [1, 359]; band rows j = c-48+d
        float xg = -3e38f, vc = 0.0f;
        bool actc = (tid >= 1 && tid < CCOLS);
        if (actc) {
            int c = tid;
            int dlo = max(0, MAXD - c);
            int dhi = min(MAXD - 1, (CCOLS - 1) - c);
            float m = -3e38f;
            for (int d = dlo; d <= dhi; ++d) {
                int j = c - MAXD + d;
                m = fmaxf(m, s_f[j] + s_sc[d * WROWS + j]);
            }
            float sum = 0.0f;
            for (int d = dlo; d <= dhi; ++d) {
                int j = c - MAXD + d;
                sum += __expf(s_f[j] + s_sc[d * WROWS + j] - m);
            }
            float A = m + __logf(sum);
            vc = TAU * (LOG_B - A) - KAPPA * sminF;
            xg = -vc * INVRHO + LOG_B;
        }
        float sig_g = -RHO * block_lse(xg, actc, red_m, red_s);
        if (actc) s_g[tid] = vc + XI * sig_g;
        float sminG = (1.0f + XI) * sig_g;   // smin of final g (exact identity)
        __syncthreads();                     // g visible

        // row pass: j = tid in [0, 311]; band cols c = j+48-d
        float xf = -3e38f, wj = 0.0f;
        bool actr = (tid < WROWS);
        if (actr) {
            int j = tid;
            float m = -3e38f;
            #pragma unroll 4
            for (int d = 0; d < MAXD; ++d)
                m = fmaxf(m, s_g[j + MAXD - d] + s_sc[d * WROWS + j]);
            float sum = 0.0f;
            #pragma unroll 4
            for (int d = 0; d < MAXD; ++d)
                sum += __expf(s_g[j + MAXD - d] + s_sc[d * WROWS + j] - m);
            float Bv = m + __logf(sum);
            wj = TAU * (LOG_A - Bv) - KAPPA * sminG;
            xf = -wj * INVRHO + LOG_A;
        }
        float sig_f = -RHO * block_lse(xf, actr, red_m, red_s);
        if (actr) s_f[tid] = wj + XI * sig_f;
        sminF = (1.0f + XI) * sig_f;
        __syncthreads();                     // f visible for next iter
    }

    // ---- final transport plan -> disparity ----
    if (tid < WROWS) {
        int j = tid;
        float fj = s_f[j];
        float num = 0.0f, den = 0.0f;
        #pragma unroll 4
        for (int d = 0; d < MAXD; ++d) {
            float p = __expf(fj + s_g[j + MAXD - d] + s_sc[d * WROWS + j]);
            den += p;
            num += (float)d * p;
        }
        out[(size_t)bid * WROWS + j] = num / fmaxf(den, 1e-8f);
    }
}

extern "C" void kernel_launch(void* const* d_in, const int* in_sizes, int n_in,
                              void* d_out, int out_size, void* d_ws, size_t ws_size,
                              hipStream_t stream) {
    const float* scores = (const float*)d_in[0];
    float* out = (float*)d_out;
    ot_disp_kernel<<<128, NT, 0, stream>>>(scores, out);
}

// Round 2
// 62.460 us; speedup vs baseline: 1.5125x; 1.5125x over previous
//
#include <hip/hip_runtime.h>
#include <math.h>

// OT disparity: banded unbalanced Sinkhorn, register-resident scores,
// 2-way d-split (thread pairs), one (b,h) problem per block.

#define MAXD   48
#define WROWS  312
#define CCOLS  360
#define NITER  10
#define NT     768
#define NWAVE  (NT / 64)
#define KD     24           // band entries per thread (48 / 2)

__device__ __forceinline__ void lse_comb(float& m, float& s, float m2, float s2) {
    float nm = fmaxf(m, m2);
    s = s * __expf(m - nm) + s2 * __expf(m2 - nm);
    m = nm;
}

// wave-level LSE partial reduce; lane0 of each wave writes (m,s) to scratch.
__device__ __forceinline__ void wave_lse_leader(float x, bool active,
                                                float* rm, float* rs) {
    float m = active ? x : -3e38f;
    float s = active ? 1.0f : 0.0f;
    #pragma unroll
    for (int off = 32; off >= 1; off >>= 1) {
        float m2 = __shfl_xor(m, off);
        float s2 = __shfl_xor(s, off);
        lse_comb(m, s, m2, s2);
    }
    int wid = threadIdx.x >> 6;
    if ((threadIdx.x & 63) == 0) { rm[wid] = m; rs[wid] = s; }
}

__device__ __forceinline__ float red_combine(const float* rm, const float* rs) {
    float M = -3e38f, S = 0.0f;
    #pragma unroll
    for (int w = 0; w < NWAVE; ++w) lse_comb(M, S, rm[w], rs[w]);
    return M + __logf(S);
}

__global__ __launch_bounds__(NT)
void ot_disp_kernel(const float* __restrict__ scores, float* __restrict__ out) {
    const int bid  = blockIdx.x;     // 0..127 (= b*64 + h)
    const int tid  = threadIdx.x;
    const int half = tid >> 1;       // column c (col pass) / row j (row pass)
    const int sub  = tid & 1;

    const float LOG_A  = -5.7430032f;   // log(1/312)
    const float LOG_B  = -5.8861040f;   // log(1/360)
    const float TAU    = 0.95f;
    const float KAPPA  = 0.025f;
    const float XI     = 0.025641026f;
    const float RHO    = 19.0f;
    const float INVRHO = 0.052631579f;

    __shared__ float s_f[WROWS];
    __shared__ float s_g[CCOLS];
    __shared__ float redA_m[NWAVE], redA_s[NWAVE];   // g-phase scratch
    __shared__ float redB_m[NWAVE], redB_s[NWAVE];   // f-phase / init scratch

    const int b = bid >> 6, h = bid & 63;
    const float* src = scores + ((size_t)b * MAXD * 64 + h) * WROWS;
    const size_t dstride = (size_t)64 * WROWS;

    const bool rowAct = (half < WROWS);
    const bool colAct = (half >= 1 && half < CCOLS);
    const int  gbase  = half + MAXD - sub;   // row pass: g index = gbase - 2k

    // ---- register caches: fixed across all iterations ----
    float rrow[KD];   // s[d][half] for d = sub+2k        (row pass, init, final)
    float rcol[KD];   // s[d][half-48+d], sentinel if OOB (column pass)
    int   cidx[KD];   // clamped f-index for column pass
    #pragma unroll
    for (int k = 0; k < KD; ++k) {
        const int d = sub + 2 * k;
        if (rowAct) rrow[k] = src[dstride * d + half]; else rrow[k] = -3e38f;
        int j = half - MAXD + d;
        bool v = colAct && ((unsigned)j < (unsigned)WROWS);
        cidx[k] = v ? j : 0;
        if (v) rcol[k] = src[dstride * d + j]; else rcol[k] = -3e38f;
    }

    // ---- init f: f_j = -log_b - LSE_d(score) ; sminF = smin(f, log_a) ----
    float sminF;
    {
        float m0=-3e38f,m1=-3e38f,m2=-3e38f,m3=-3e38f;
        #pragma unroll
        for (int k = 0; k < KD; k += 4) {
            m0 = fmaxf(m0, rrow[k]);   m1 = fmaxf(m1, rrow[k+1]);
            m2 = fmaxf(m2, rrow[k+2]); m3 = fmaxf(m3, rrow[k+3]);
        }
        float m = fmaxf(fmaxf(m0, m1), fmaxf(m2, m3));
        m = fmaxf(m, __shfl_xor(m, 1));
        float s0=0,s1=0,s2=0,s3=0;
        #pragma unroll
        for (int k = 0; k < KD; k += 4) {
            s0 += __expf(rrow[k]-m);   s1 += __expf(rrow[k+1]-m);
            s2 += __expf(rrow[k+2]-m); s3 += __expf(rrow[k+3]-m);
        }
        float s = (s0+s1)+(s2+s3);
        s += __shfl_xor(s, 1);
        float fj = -LOG_B - (m + __logf(s));
        if (rowAct && sub == 0) s_f[half] = fj;
        float x = -fj * INVRHO + LOG_A;
        wave_lse_leader(x, rowAct && sub == 0, redB_m, redB_s);
        __syncthreads();                                  // S0: s_f + redB ready
        sminF = -RHO * red_combine(redB_m, redB_s);
    }

    float fval = 0.0f;   // this thread's final f (kept for the epilogue)

    // ---- Sinkhorn iterations ----
    for (int it = 0; it < NITER; ++it) {
        // ---- column pass: A_c = LSE over band of (f_j + score) ----
        float t[KD];
        {
            float m0=-3e38f,m1=-3e38f,m2=-3e38f,m3=-3e38f;
            #pragma unroll
            for (int k = 0; k < KD; k += 4) {
                t[k]   = s_f[cidx[k]]   + rcol[k];
                t[k+1] = s_f[cidx[k+1]] + rcol[k+1];
                t[k+2] = s_f[cidx[k+2]] + rcol[k+2];
                t[k+3] = s_f[cidx[k+3]] + rcol[k+3];
                m0 = fmaxf(m0, t[k]);   m1 = fmaxf(m1, t[k+1]);
                m2 = fmaxf(m2, t[k+2]); m3 = fmaxf(m3, t[k+3]);
            }
            float cm = fmaxf(fmaxf(m0, m1), fmaxf(m2, m3));
            cm = fmaxf(cm, __shfl_xor(cm, 1));
            float s0=0,s1=0,s2=0,s3=0;
            #pragma unroll
            for (int k = 0; k < KD; k += 4) {
                s0 += __expf(t[k]-cm);   s1 += __expf(t[k+1]-cm);
                s2 += __expf(t[k+2]-cm); s3 += __expf(t[k+3]-cm);
            }
            float cs = (s0+s1)+(s2+s3);
            cs += __shfl_xor(cs, 1);
            // sentinel entries underflow to 0 in exp; empty columns (c=0,
            // c>=360) give garbage vc but are fully masked below.
            float vc = TAU * (LOG_B - (cm + __logf(cs))) - KAPPA * sminF;
            float xg = (colAct && sub == 0) ? (-vc * INVRHO + LOG_B) : -3e38f;
            wave_lse_leader(xg, colAct && sub == 0, redA_m, redA_s);
            __syncthreads();                              // S1
            float sig_g = -RHO * red_combine(redA_m, redA_s);
            if (colAct && sub == 0) s_g[half] = vc + XI * sig_g;
            float sminG = (1.0f + XI) * sig_g;            // smin of final g
            __syncthreads();                              // S2: s_g visible

            // ---- row pass: B_j = LSE_d(g + score) ----
            float wj = 0.0f;
            float rm = -3e38f, rsum = 0.0f;
            if (rowAct) {
                float n0=-3e38f,n1=-3e38f,n2=-3e38f,n3=-3e38f;
                #pragma unroll
                for (int k = 0; k < KD; k += 4) {
                    t[k]   = s_g[gbase - 2*k]     + rrow[k];
                    t[k+1] = s_g[gbase - 2*(k+1)] + rrow[k+1];
                    t[k+2] = s_g[gbase - 2*(k+2)] + rrow[k+2];
                    t[k+3] = s_g[gbase - 2*(k+3)] + rrow[k+3];
                    n0 = fmaxf(n0, t[k]);   n1 = fmaxf(n1, t[k+1]);
                    n2 = fmaxf(n2, t[k+2]); n3 = fmaxf(n3, t[k+3]);
                }
                rm = fmaxf(fmaxf(n0, n1), fmaxf(n2, n3));
            }
            rm = fmaxf(rm, __shfl_xor(rm, 1));
            if (rowAct) {
                float s0=0,s1=0,s2=0,s3=0;
                #pragma unroll
                for (int k = 0; k < KD; k += 4) {
                    s0 += __expf(t[k]-rm);   s1 += __expf(t[k+1]-rm);
                    s2 += __expf(t[k+2]-rm); s3 += __expf(t[k+3]-rm);
                }
                rsum = (s0+s1)+(s2+s3);
            }
            rsum += __shfl_xor(rsum, 1);
            if (rowAct) {
                float Bv = rm + __logf(rsum);
                wj = TAU * (LOG_A - Bv) - KAPPA * sminG;
            }
            float xf = (rowAct && sub == 0) ? (-wj * INVRHO + LOG_A) : -3e38f;
            wave_lse_leader(xf, rowAct && sub == 0, redB_m, redB_s);
            __syncthreads();                              // S3
            float sig_f = -RHO * red_combine(redB_m, redB_s);
            fval = wj + XI * sig_f;
            if (rowAct && sub == 0) s_f[half] = fval;
            sminF = (1.0f + XI) * sig_f;
            __syncthreads();                              // S4: s_f visible
        }
    }

    // ---- epilogue: P = exp(f + g + score) on band; disp = sum(d*P)/sum(P) ----
    float num = 0.0f, den = 0.0f;
    if (rowAct) {
        float d0=0,d1=0,n0=0,n1=0;
        #pragma unroll
        for (int k = 0; k < KD; k += 2) {
            float p0 = __expf(fval + s_g[gbase - 2*k]     + rrow[k]);
            float p1 = __expf(fval + s_g[gbase - 2*(k+1)] + rrow[k+1]);
            d0 += p0; d1 += p1;
            n0 += (float)(sub + 2*k)     * p0;
            n1 += (float)(sub + 2*(k+1)) * p1;
        }
        den = d0 + d1; num = n0 + n1;
    }
    den += __shfl_xor(den, 1);
    num += __shfl_xor(num, 1);
    if (rowAct && sub == 0)
        out[(size_t)bid * WROWS + half] = num / fmaxf(den, 1e-8f);
}

extern "C" void kernel_launch(void* const* d_in, const int* in_sizes, int n_in,
                              void* d_out, int out_size, void* d_ws, size_t ws_size,
                              hipStream_t stream) {
    const float* scores = (const float*)d_in[0];
    float* out = (float*)d_out;
    ot_disp_kernel<<<128, NT, 0, stream>>>(scores, out);
}

// Round 3
// 32.690 us; speedup vs baseline: 2.8899x; 1.9107x over previous
//
#include <hip/hip_runtime.h>
#include <math.h>

// Banded unbalanced Sinkhorn OT -> disparity. One (b,h) problem per block.
// All math in log2 domain. No max-stabilization (ranges audited: |exp args|
// stay < 40 bits of fp32 range; sentinels underflow to exact 0).

#define MAXD   48
#define WROWS  312
#define CCOLS  360
#define NITER  10
#define NT     768
#define NWAVE  (NT / 64)
#define KD     24          // band entries per thread (contiguous d-halves)

__device__ __forceinline__ float wave_sum64(float e) {
    #pragma unroll
    for (int off = 32; off >= 1; off >>= 1) e += __shfl_xor(e, off);
    return e;
}

// log2 of the sum of the 12 per-wave partial sums (LDS broadcast reads)
__device__ __forceinline__ float comb12(const float* r) {
    const float4* q = (const float4*)r;
    float4 a = q[0], b = q[1], c = q[2];
    float s = ((a.x + a.y) + (a.z + a.w))
            + (((b.x + b.y) + (b.z + b.w)) + ((c.x + c.y) + (c.z + c.w)));
    return __builtin_amdgcn_logf(s);   // v_log_f32 = log2
}

__global__ __launch_bounds__(NT)
void ot_disp_kernel(const float* __restrict__ scores, float* __restrict__ out) {
    const int bid  = blockIdx.x;     // 0..127 (= b*64 + h)
    const int tid  = threadIdx.x;
    const int half = tid >> 1;       // column c (col pass) / row j (row pass)
    const int sub  = tid & 1;
    const int wid  = tid >> 6;
    const bool ld  = ((tid & 63) == 0);

    const float LOG2E  = 1.4426950408889634f;
    const float LOG_A2 = -8.285402f;     // -log2(312)
    const float LOG_B2 = -8.491853f;     // -log2(360)
    const float TAU    = 0.95f;
    const float KAPPA  = 0.025f;
    const float XI     = 0.025641026f;
    const float RHO    = 19.0f;
    const float INVRHO = 0.052631579f;

    __shared__ float s_fb[MAXD + WROWS + MAXD];   // f with zero guards
    __shared__ float s_g[CCOLS];
    __shared__ __align__(16) float redA[NWAVE];
    __shared__ __align__(16) float redB[NWAVE];
    float* const s_f = s_fb + MAXD;

    const bool rowAct = (half < WROWS);
    const bool colAct = (half >= 1 && half < CCOLS);

    const int b = bid >> 6, h = bid & 63;
    const float* src = scores + ((size_t)b * MAXD * 64 + h) * WROWS;
    const size_t dstr = (size_t)64 * WROWS;

    if (tid < MAXD) { s_fb[tid] = 0.0f; s_fb[MAXD + WROWS + tid] = 0.0f; }

    const int d0 = sub * KD;                      // this thread's d-range start
    const int jb = (colAct ? half : 0) - MAXD + d0;   // col band: j = jb + k
    const int jr = rowAct ? half : 0;

    // register caches (log2-scaled), fixed across all iterations
    float rrow[KD];   // s2[d0+k][jr]
    float rcol[KD];   // s2[d0+k][jb+k], sentinel if OOB
    #pragma unroll
    for (int k = 0; k < KD; ++k) {
        rrow[k] = src[dstr * (d0 + k) + jr] * LOG2E;
        int j = jb + k;
        rcol[k] = (colAct && (unsigned)j < (unsigned)WROWS)
                      ? src[dstr * (d0 + k) + j] * LOG2E : -3e38f;
    }

    // ---- init f: f = -LOG_B2 - log2(sum exp2(score)); reduce smin(f) ----
    float fshift = 0.0f, sminF;
    {
        float e0=0,e1=0,e2=0,e3=0;
        #pragma unroll
        for (int k = 0; k < KD; k += 4) {
            e0 += __builtin_amdgcn_exp2f(rrow[k]);
            e1 += __builtin_amdgcn_exp2f(rrow[k+1]);
            e2 += __builtin_amdgcn_exp2f(rrow[k+2]);
            e3 += __builtin_amdgcn_exp2f(rrow[k+3]);
        }
        float s = (e0+e1)+(e2+e3);
        s += __shfl_xor(s, 1);
        float fj = -LOG_B2 - __builtin_amdgcn_logf(s);
        bool own = rowAct && (sub == 0);
        if (own) s_f[half] = fj;
        float xs = own ? __builtin_amdgcn_exp2f(-fj * INVRHO + LOG_A2) : 0.0f;
        float ws = wave_sum64(xs);
        if (ld) redB[wid] = ws;
        __syncthreads();
        sminF = -RHO * comb12(redB);
    }

    // ---- Sinkhorn iterations: 2 syncs per iteration ----
    float wv = 0.0f, gshift = 0.0f;
    for (int it = 0; it < NITER; ++it) {
        // col phase: A_raw = log2 sum exp2(f_raw + score) over band
        float e0=0,e1=0,e2=0,e3=0;
        #pragma unroll
        for (int k = 0; k < KD; k += 4) {
            e0 += __builtin_amdgcn_exp2f(s_f[jb+k]   + rcol[k]);
            e1 += __builtin_amdgcn_exp2f(s_f[jb+k+1] + rcol[k+1]);
            e2 += __builtin_amdgcn_exp2f(s_f[jb+k+2] + rcol[k+2]);
            e3 += __builtin_amdgcn_exp2f(s_f[jb+k+3] + rcol[k+3]);
        }
        float cs = (e0+e1)+(e2+e3);
        cs += __shfl_xor(cs, 1);
        float Cg = TAU * (LOG_B2 - fshift) - KAPPA * sminF;
        float vc = Cg - TAU * __builtin_amdgcn_logf(cs);   // raw g (pre-XI)
        bool ownC = colAct && (sub == 0);
        if (ownC) s_g[half] = vc;
        float xs = ownC ? __builtin_amdgcn_exp2f(-vc * INVRHO + LOG_B2) : 0.0f;
        float ws = wave_sum64(xs);
        if (ld) redA[wid] = ws;
        __syncthreads();                                   // S1: s_g + redA
        float sg = -RHO * comb12(redA);
        gshift = XI * sg;
        float sminG = (1.0f + XI) * sg;

        // row phase: B_raw = log2 sum exp2(g_raw + score) over band
        float f0=0,f1=0,f2=0,f3=0;
        const int gb = jr + MAXD - d0;                     // g idx = gb - k
        #pragma unroll
        for (int k = 0; k < KD; k += 4) {
            f0 += __builtin_amdgcn_exp2f(s_g[gb-k]   + rrow[k]);
            f1 += __builtin_amdgcn_exp2f(s_g[gb-k-1] + rrow[k+1]);
            f2 += __builtin_amdgcn_exp2f(s_g[gb-k-2] + rrow[k+2]);
            f3 += __builtin_amdgcn_exp2f(s_g[gb-k-3] + rrow[k+3]);
        }
        float rs = (f0+f1)+(f2+f3);
        rs += __shfl_xor(rs, 1);
        float Cf = TAU * (LOG_A2 - gshift) - KAPPA * sminG;
        wv = Cf - TAU * __builtin_amdgcn_logf(rs);         // raw f (pre-XI)
        bool ownR = rowAct && (sub == 0);
        if (ownR) s_f[half] = wv;
        float xf = ownR ? __builtin_amdgcn_exp2f(-wv * INVRHO + LOG_A2) : 0.0f;
        float wf = wave_sum64(xf);
        if (ld) redB[wid] = wf;
        __syncthreads();                                   // S2: s_f + redB
        float sf = -RHO * comb12(redB);
        fshift = XI * sf;
        sminF = (1.0f + XI) * sf;
    }

    // ---- epilogue: P = exp2(f_full + g_full + score); disp = sum(d*P)/sum(P)
    float num = 0.0f, den = 0.0f;
    if (rowAct) {
        float base = wv + fshift + gshift;
        const int gb = half + MAXD - d0;
        float p0a=0,p1a=0,n0=0,n1=0;
        #pragma unroll
        for (int k = 0; k < KD; k += 2) {
            float p0 = __builtin_amdgcn_exp2f(base + s_g[gb-k]   + rrow[k]);
            float p1 = __builtin_amdgcn_exp2f(base + s_g[gb-k-1] + rrow[k+1]);
            p0a += p0; p1a += p1;
            n0 += (float)(d0 + k) * p0;
            n1 += (float)(d0 + k + 1) * p1;
        }
        den = p0a + p1a; num = n0 + n1;
    }
    den += __shfl_xor(den, 1);
    num += __shfl_xor(num, 1);
    if (rowAct && sub == 0)
        out[(size_t)bid * WROWS + half] = num / fmaxf(den, 1e-8f);
}

extern "C" void kernel_launch(void* const* d_in, const int* in_sizes, int n_in,
                              void* d_out, int out_size, void* d_ws, size_t ws_size,
                              hipStream_t stream) {
    const float* scores = (const float*)d_in[0];
    float* out = (float*)d_out;
    ot_disp_kernel<<<128, NT, 0, stream>>>(scores, out);
}

// Round 5
// 26.348 us; speedup vs baseline: 3.5855x; 1.2407x over previous
//
#include <hip/hip_runtime.h>
#include <math.h>

// Banded unbalanced Sinkhorn OT -> disparity. One (b,h) problem per block.
// Potentials kept as EXPONENTIALS (E=2^f, G=2^g) in LDS; score exponentials
// w=e^s precomputed in registers -> band loops are pure FMA. Reductions via
// DPP + one ds_add_f32 per wave into per-phase accumulator slots.

#define MAXD   48
#define WROWS  312
#define CCOLS  360
#define NITER  10
#define NT     768
#define KD     24          // band entries per thread (contiguous d-halves)
#define NPHASE (2 * NITER + 1)

// quad_perm [1,0,3,2]: both lanes of a pair get the pair sum
__device__ __forceinline__ float pair_sum(float x) {
    int y = __builtin_amdgcn_update_dpp(0, __float_as_int(x), 0xB1, 0xf, 0xf, true);
    return x + __int_as_float(y);
}

template <int CTRL>
__device__ __forceinline__ float dpp_add(float x, float acc) {
    int y = __builtin_amdgcn_update_dpp(0, __float_as_int(x), CTRL, 0xf, 0xf, true);
    return acc + __int_as_float(y);
}

// 64-lane sum; valid in lane 63 only.
__device__ __forceinline__ float dpp_sum64(float x) {
    x = dpp_add<0x111>(x, x);   // row_shr:1
    x = dpp_add<0x112>(x, x);   // row_shr:2
    x = dpp_add<0x114>(x, x);   // row_shr:4
    x = dpp_add<0x118>(x, x);   // row_shr:8
    x = dpp_add<0x142>(x, x);   // row_bcast:15
    x = dpp_add<0x143>(x, x);   // row_bcast:31
    return x;
}

__global__ __launch_bounds__(NT)
void ot_disp_kernel(const float* __restrict__ scores, float* __restrict__ out) {
    const int bid  = blockIdx.x;     // 0..127 (= b*64 + h)
    const int tid  = threadIdx.x;
    const int half = tid >> 1;       // column c (col pass) / row j (row pass)
    const int sub  = tid & 1;

    const float LOG_A2 = -8.285402f;     // -log2(312)
    const float LOG_B2 = -8.491853f;     // -log2(360)
    const float TAU    = 0.95f;
    const float KAPPA  = 0.025f;
    const float XI     = 0.025641026f;
    const float RHO    = 19.0f;
    const float INVRHO = 0.052631579f;

    __shared__ float s_Eb[MAXD + WROWS + MAXD];   // E = 2^f with zero guards
    __shared__ float s_G[CCOLS];                  // G = 2^g
    __shared__ float s_acc[NPHASE];               // per-phase reduction slots
    float* const s_E = s_Eb + MAXD;

    const bool rowAct = (half < WROWS);
    const bool colAct = (half >= 1 && half < CCOLS);

    const int b = bid >> 6, h = bid & 63;
    const float* src = scores + ((size_t)b * MAXD * 64 + h) * WROWS;
    const size_t dstr = (size_t)64 * WROWS;

    if (tid < NPHASE) s_acc[tid] = 0.0f;
    if (tid < MAXD) { s_Eb[tid] = 0.0f; s_Eb[MAXD + WROWS + tid] = 0.0f; }

    const int d0 = sub * KD;
    const int jb = (colAct ? half : 0) - MAXD + d0;   // col band: E idx = jb + k
    const int jr = rowAct ? half : 0;
    const int gb = jr + MAXD - d0;                    // row band: G idx = gb - k

    // ---- register caches: w = e^score, fixed across all iterations ----
    float wrow[KD];   // e^s[d0+k][jr]
    float wcol[KD];   // e^s[d0+k][jb+k], 0 if OOB
    #pragma unroll
    for (int k = 0; k < KD; ++k) {
        wrow[k] = __expf(src[dstr * (d0 + k) + jr]);
        int j = jb + k;
        bool v = colAct && ((unsigned)j < (unsigned)WROWS);
        float sv = src[dstr * (d0 + k) + (v ? j : 0)];
        wcol[k] = v ? __expf(sv) : 0.0f;
    }
    __syncthreads();   // B0: accs zeroed + guards set before any ds_add/reads

    // ---- init: f = -LOG_B2 - log2(sum w); reduce smin(f) into acc[0] ----
    float sminF;
    {
        float e0=0,e1=0,e2=0,e3=0;
        #pragma unroll
        for (int k = 0; k < KD; k += 4) {
            e0 += wrow[k]; e1 += wrow[k+1]; e2 += wrow[k+2]; e3 += wrow[k+3];
        }
        float s = pair_sum((e0+e1)+(e2+e3));
        float f2 = -LOG_B2 - __builtin_amdgcn_logf(s);
        bool own = rowAct && (sub == 0);
        if (own) s_E[half] = __builtin_amdgcn_exp2f(f2);
        float xs = own ? __builtin_amdgcn_exp2f(-f2 * INVRHO + LOG_A2) : 0.0f;
        float t = dpp_sum64(xs);
        if ((tid & 63) == 63) atomicAdd(&s_acc[0], t);
        __syncthreads();                              // B1
        sminF = -RHO * __builtin_amdgcn_logf(s_acc[0]);
    }

    // ---- Sinkhorn iterations: 2 syncs per iteration, band loops = pure FMA
    float wv = 0.0f, gshift = 0.0f, fshift = 0.0f;
    for (int it = 0; it < NITER; ++it) {
        // col phase: cs = sum_k w * E over band
        float e0=0,e1=0,e2=0,e3=0;
        #pragma unroll
        for (int k = 0; k < KD; k += 4) {
            e0 = fmaf(wcol[k],   s_E[jb+k],   e0);
            e1 = fmaf(wcol[k+1], s_E[jb+k+1], e1);
            e2 = fmaf(wcol[k+2], s_E[jb+k+2], e2);
            e3 = fmaf(wcol[k+3], s_E[jb+k+3], e3);
        }
        float cs = pair_sum((e0+e1)+(e2+e3));
        float Cg = TAU * (LOG_B2 - fshift) - KAPPA * sminF;
        float vc = Cg - TAU * __builtin_amdgcn_logf(cs);   // raw g (pre-XI)
        bool ownC = colAct && (sub == 0);
        if (ownC) s_G[half] = __builtin_amdgcn_exp2f(vc);
        float xs = ownC ? __builtin_amdgcn_exp2f(-vc * INVRHO + LOG_B2) : 0.0f;
        float tg = dpp_sum64(xs);
        if ((tid & 63) == 63) atomicAdd(&s_acc[1 + 2*it], tg);
        __syncthreads();                              // S1: s_G + acc ready
        float sg = -RHO * __builtin_amdgcn_logf(s_acc[1 + 2*it]);
        gshift = XI * sg;
        float sminG = (1.0f + XI) * sg;

        // row phase: rs = sum_k w * G over band
        float f0=0,f1=0,f2=0,f3=0;
        #pragma unroll
        for (int k = 0; k < KD; k += 4) {
            f0 = fmaf(wrow[k],   s_G[gb-k],   f0);
            f1 = fmaf(wrow[k+1], s_G[gb-k-1], f1);
            f2 = fmaf(wrow[k+2], s_G[gb-k-2], f2);
            f3 = fmaf(wrow[k+3], s_G[gb-k-3], f3);
        }
        float rs = pair_sum((f0+f1)+(f2+f3));
        float Cf = TAU * (LOG_A2 - gshift) - KAPPA * sminG;
        wv = Cf - TAU * __builtin_amdgcn_logf(rs);         // raw f (pre-XI)
        bool ownR = rowAct && (sub == 0);
        if (ownR) s_E[half] = __builtin_amdgcn_exp2f(wv);
        float xf = ownR ? __builtin_amdgcn_exp2f(-wv * INVRHO + LOG_A2) : 0.0f;
        float tf = dpp_sum64(xf);
        if ((tid & 63) == 63) atomicAdd(&s_acc[2 + 2*it], tf);
        __syncthreads();                              // S2: s_E + acc ready
        float sf = -RHO * __builtin_amdgcn_logf(s_acc[2 + 2*it]);
        fshift = XI * sf;
        sminF = (1.0f + XI) * sf;
    }

    // ---- epilogue: P = E*G*w on band; disp = sum(d*P)/clip(sum(P)) ----
    float num = 0.0f, den = 0.0f;
    if (rowAct) {
        float d0a=0,d1a=0,n0=0,n1=0;
        #pragma unroll
        for (int k = 0; k < KD; k += 2) {
            float p0 = wrow[k]   * s_G[gb-k];
            float p1 = wrow[k+1] * s_G[gb-k-1];
            d0a += p0; d1a += p1;
            n0 += (float)(d0 + k)     * p0;
            n1 += (float)(d0 + k + 1) * p1;
        }
        den = d0a + d1a; num = n0 + n1;
    }
    den = pair_sum(den);
    num = pair_sum(num);
    if (rowAct && sub == 0) {
        float E = __builtin_amdgcn_exp2f(wv + fshift + gshift);
        float mass = fmaxf(E * den, 1e-8f);
        out[(size_t)bid * WROWS + half] = (E * num) / mass;
    }
}

extern "C" void kernel_launch(void* const* d_in, const int* in_sizes, int n_in,
                              void* d_out, int out_size, void* d_ws, size_t ws_size,
                              hipStream_t stream) {
    const float* scores = (const float*)d_in[0];
    float* out = (float*)d_out;
    ot_disp_kernel<<<128, NT, 0, stream>>>(scores, out);
}

// Round 6
// 25.982 us; speedup vs baseline: 3.6360x; 1.0141x over previous
//
#include <hip/hip_runtime.h>
#include <math.h>

// Banded unbalanced Sinkhorn OT -> disparity. One (b,h) problem per block.
// Band iteration is scalar-free: Ghat = (sum w*Ehat)^-tau, Ehat' = (sum w*Ghat)^-tau.
// All uniform shifts ride in a scalar recurrence evaluated ONCE at the end from
// 21 block-reduction values (fire-and-forget ds_add into per-phase slots).
// E/G stored in parity-duplicated LDS arrays -> aligned float2 band reads.

#define MAXD   48
#define WROWS  312
#define CCOLS  360
#define NITER  10
#define NT     768
#define KD     24
#define NACC   (2 * NITER + 1)

// quad_perm [1,0,3,2]: both lanes of a pair get the pair sum
__device__ __forceinline__ float pair_sum(float x) {
    int y = __builtin_amdgcn_update_dpp(0, __float_as_int(x), 0xB1, 0xf, 0xf, true);
    return x + __int_as_float(y);
}
template <int CTRL>
__device__ __forceinline__ float dpp_add(float x, float acc) {
    int y = __builtin_amdgcn_update_dpp(0, __float_as_int(x), CTRL, 0xf, 0xf, true);
    return acc + __int_as_float(y);
}
// 64-lane sum; valid in lane 63 only.
__device__ __forceinline__ float dpp_sum64(float x) {
    x = dpp_add<0x111>(x, x);   // row_shr:1
    x = dpp_add<0x112>(x, x);   // row_shr:2
    x = dpp_add<0x114>(x, x);   // row_shr:4
    x = dpp_add<0x118>(x, x);   // row_shr:8
    x = dpp_add<0x142>(x, x);   // row_bcast:15
    x = dpp_add<0x143>(x, x);   // row_bcast:31
    return x;
}

__global__ __launch_bounds__(NT)
void ot_disp_kernel(const float* __restrict__ scores, float* __restrict__ out) {
    const int bid  = blockIdx.x;     // 0..127 (= b*64 + h)
    const int tid  = threadIdx.x;
    const int half = tid >> 1;       // column c (col pass) / row j (row pass)
    const int sub  = tid & 1;

    const float LOG_A2 = -8.2854022f;    // -log2(312)
    const float LOG_B2 = -8.4918531f;    // -log2(360)
    const float TAU    = 0.95f;
    const float KAPPA  = 0.025f;
    const float XI     = 0.025641026f;
    const float RHO    = 19.0f;
    const float INVRHO = 0.052631579f;
    const float TIR    = 0.05f;          // TAU/RHO

    // E bufpos = j+48, j in [-48,360) -> 408 floats; EB[i] = EA[i-1] (410)
    // G index  = c in [0,360) -> 360 floats;        GB[i] = GA[i-1] (362)
    __shared__ float2 sEA[204], sEB[205], sGA[180], sGB[181];
    __shared__ float  s_acc[NACC];
    float* const EAf = (float*)sEA;  float* const EBf = (float*)sEB;
    float* const GAf = (float*)sGA;  float* const GBf = (float*)sGB;

    // zero-fill everything (guards + acc slots) before first use
    if (tid < 205) {
        sEB[tid] = make_float2(0.f, 0.f);
        if (tid < 204) sEA[tid] = make_float2(0.f, 0.f);
        if (tid < 181) sGB[tid] = make_float2(0.f, 0.f);
        if (tid < 180) sGA[tid] = make_float2(0.f, 0.f);
    }
    if (tid < NACC) s_acc[tid] = 0.f;

    const bool rowAct = (half < WROWS);
    const bool colAct = (half >= 1 && half < CCOLS);
    const int b = bid >> 6, h = bid & 63;
    const float* src = scores + ((size_t)(b * MAXD) * 64 + h) * WROWS;
    const size_t dstr = (size_t)64 * WROWS;
    const int d0 = sub * KD;
    const int jr = rowAct ? half : 0;
    const int jc = colAct ? half : 0;

    // ---- register weight caches (fixed across all iterations) ----
    float wcol[KD];    // e^s[d0+m][c-48+d0+m], 0 if OOB   (col band, ascending)
    float wrowR[KD];   // e^s[d0+23-m][j]                  (row band, window order)
    #pragma unroll
    for (int m = 0; m < KD; ++m) {
        wrowR[m] = __expf(src[dstr * (size_t)(d0 + 23 - m) + jr]);
        int j = jc - MAXD + d0 + m;
        bool v = colAct && ((unsigned)j < (unsigned)WROWS);
        float sv = src[dstr * (size_t)(d0 + m) + (v ? j : 0)];
        wcol[m] = v ? __expf(sv) : 0.0f;
    }

    // parity-matched band base pointers (fixed across iterations)
    const int pe = jc + d0;                 // E bufpos window start (= jb+48)
    const float2* const ep = (pe & 1) ? (sEB + ((pe + 1) >> 1)) : (sEA + (pe >> 1));
    const int qg = jr + 25 - d0;            // G window start (= gb-23)
    const float2* const gp = (qg & 1) ? (sGB + ((qg + 1) >> 1)) : (sGA + (qg >> 1));

    __syncthreads();   // B0: zeros visible

    // ---- init: Ehat0 = 1/sum(w); reduction y0 = 2^(lsum/RHO + LOG_A2) ----
    {
        float a0=0,a1=0,a2=0,a3=0;
        #pragma unroll
        for (int m = 0; m < KD; m += 4) {
            a0 += wrowR[m];   a1 += wrowR[m+1];
            a2 += wrowR[m+2]; a3 += wrowR[m+3];
        }
        float s  = pair_sum((a0 + a1) + (a2 + a3));
        float ls = __builtin_amdgcn_logf(s);
        float eh = __builtin_amdgcn_exp2f(-ls);
        bool own = rowAct && (sub == 0);
        if (own) { EAf[half + MAXD] = eh; EBf[half + MAXD + 1] = eh; }
        float yv = __builtin_amdgcn_exp2f(fmaf(INVRHO, ls, LOG_A2));
        float t  = dpp_sum64(own ? yv : 0.0f);
        if ((tid & 63) == 63) atomicAdd(&s_acc[0], t);
        __syncthreads();
    }

    // ---- Sinkhorn iterations: 1 barrier per phase, no scalar deps ----
    float2 gv[12];
    float ehat = 0.f, den = 0.f;
    for (int it = 0; it < NITER; ++it) {
        // col phase: Ghat_c = (sum_d w * Ehat)^-TAU
        float a0=0,a1=0,a2=0,a3=0;
        #pragma unroll
        for (int u = 0; u < 12; u += 2) {
            float2 v0 = ep[u], v1 = ep[u+1];
            a0 = fmaf(wcol[2*u],   v0.x, a0);
            a1 = fmaf(wcol[2*u+1], v0.y, a1);
            a2 = fmaf(wcol[2*u+2], v1.x, a2);
            a3 = fmaf(wcol[2*u+3], v1.y, a3);
        }
        float cs  = pair_sum((a0 + a1) + (a2 + a3));
        float lcs = __builtin_amdgcn_logf(cs);
        float gh  = __builtin_amdgcn_exp2f(-TAU * lcs);
        bool ownC = colAct && (sub == 0);
        if (ownC) { GAf[half] = gh; GBf[half + 1] = gh; }
        float yv = __builtin_amdgcn_exp2f(fmaf(TIR, lcs, LOG_B2));
        float tg = dpp_sum64(ownC ? yv : 0.0f);
        if ((tid & 63) == 63) atomicAdd(&s_acc[1 + 2*it], tg);
        __syncthreads();                      // Ghat + slot visible

        // row phase: Ehat_j = (sum_d w * Ghat)^-TAU  (keep window in gv)
        float b0=0,b1=0,b2=0,b3=0;
        #pragma unroll
        for (int u = 0; u < 12; u += 2) {
            gv[u] = gp[u]; gv[u+1] = gp[u+1];
            b0 = fmaf(wrowR[2*u],   gv[u].x,   b0);
            b1 = fmaf(wrowR[2*u+1], gv[u].y,   b1);
            b2 = fmaf(wrowR[2*u+2], gv[u+1].x, b2);
            b3 = fmaf(wrowR[2*u+3], gv[u+1].y, b3);
        }
        den = pair_sum((b0 + b1) + (b2 + b3));
        float lrs = __builtin_amdgcn_logf(den);
        ehat = __builtin_amdgcn_exp2f(-TAU * lrs);
        bool ownR = rowAct && (sub == 0);
        if (ownR) { EAf[half + MAXD] = ehat; EBf[half + MAXD + 1] = ehat; }
        float yf = __builtin_amdgcn_exp2f(fmaf(TIR, lrs, LOG_A2));
        float tf = dpp_sum64(ownR ? yf : 0.0f);
        if ((tid & 63) == 63) atomicAdd(&s_acc[2 + 2*it], tf);
        __syncthreads();                      // Ehat + slot visible
    }

    // ---- scalar recurrence from the 21 reduction values (uniform) ----
    float R[NACC];
    #pragma unroll
    for (int t = 0; t < NACC; ++t) R[t] = __builtin_amdgcn_logf(s_acc[t]);
    float fsh   = -LOG_B2;
    float sminF = fsh - RHO * R[0];
    float gsh   = 0.f;
    #pragma unroll
    for (int it = 0; it < NITER; ++it) {
        float Cg = TAU * (LOG_B2 - fsh) - KAPPA * sminF;
        float sg = Cg - RHO * R[1 + 2*it];
        gsh = Cg + XI * sg;
        float sminG = (1.0f + XI) * sg;
        float Cf = TAU * (LOG_A2 - gsh) - KAPPA * sminG;
        float sf = Cf - RHO * R[2 + 2*it];
        fsh   = Cf + XI * sf;
        sminF = (1.0f + XI) * sf;
    }

    // ---- disparity from last row window (den = rs_last, num from gv) ----
    float n0 = 0.f, n1 = 0.f;
    #pragma unroll
    for (int u = 0; u < 12; ++u) {
        n0 = fmaf((float)(d0 + 23 - 2*u) * wrowR[2*u],   gv[u].x, n0);
        n1 = fmaf((float)(d0 + 22 - 2*u) * wrowR[2*u+1], gv[u].y, n1);
    }
    float num = pair_sum(n0 + n1);
    if (rowAct && sub == 0) {
        float E = __builtin_amdgcn_exp2f(fsh + gsh) * ehat;   // full 2^f_j
        float mass = fmaxf(E * den, 1e-8f);
        out[(size_t)bid * WROWS + half] = (E * num) / mass;
    }
}

extern "C" void kernel_launch(void* const* d_in, const int* in_sizes, int n_in,
                              void* d_out, int out_size, void* d_ws, size_t ws_size,
                              hipStream_t stream) {
    const float* scores = (const float*)d_in[0];
    float* out = (float*)d_out;
    ot_disp_kernel<<<128, NT, 0, stream>>>(scores, out);
}

// Round 7
// 24.652 us; speedup vs baseline: 3.8321x; 1.0539x over previous
//
#include <hip/hip_runtime.h>
#include <math.h>

// Banded unbalanced Sinkhorn OT -> disparity. One (b,h) problem per block.
// Band iteration is scalar-free: Ghat = (sum w*Ehat)^-tau, Ehat' = (sum w*Ghat)^-tau.
// Uniform shifts ride in a scalar recurrence evaluated ONCE at the end from 21
// block-reduction values. Per-phase partial sums go to PER-WAVE LDS slots
// (plain ds_write, no same-address atomic serialization gating the barrier).
// E/G stored in parity-duplicated LDS arrays -> aligned float2 band reads.

#define MAXD   48
#define WROWS  312
#define CCOLS  360
#define NITER  10
#define NT     768
#define NWAVE  12
#define KD     24
#define NACC   (2 * NITER + 1)

// quad_perm [1,0,3,2]: both lanes of a pair get the pair sum
__device__ __forceinline__ float pair_sum(float x) {
    int y = __builtin_amdgcn_update_dpp(0, __float_as_int(x), 0xB1, 0xf, 0xf, true);
    return x + __int_as_float(y);
}
template <int CTRL>
__device__ __forceinline__ float dpp_add(float x, float acc) {
    int y = __builtin_amdgcn_update_dpp(0, __float_as_int(x), CTRL, 0xf, 0xf, true);
    return acc + __int_as_float(y);
}
// 64-lane sum; valid in lane 63 only.
__device__ __forceinline__ float dpp_sum64(float x) {
    x = dpp_add<0x111>(x, x);   // row_shr:1
    x = dpp_add<0x112>(x, x);   // row_shr:2
    x = dpp_add<0x114>(x, x);   // row_shr:4
    x = dpp_add<0x118>(x, x);   // row_shr:8
    x = dpp_add<0x142>(x, x);   // row_bcast:15
    x = dpp_add<0x143>(x, x);   // row_bcast:31
    return x;
}

__global__ __launch_bounds__(NT)
void ot_disp_kernel(const float* __restrict__ scores, float* __restrict__ out) {
    const int bid  = blockIdx.x;     // 0..127 (= b*64 + h)
    const int tid  = threadIdx.x;
    const int half = tid >> 1;       // column c (col pass) / row j (row pass)
    const int sub  = tid & 1;
    const int wid  = tid >> 6;

    const float LOG_A2 = -8.2854022f;    // -log2(312)
    const float LOG_B2 = -8.4918531f;    // -log2(360)
    const float TAU    = 0.95f;
    const float KAPPA  = 0.025f;
    const float XI     = 0.025641026f;
    const float RHO    = 19.0f;
    const float INVRHO = 0.052631579f;
    const float TIR    = 0.05f;          // TAU/RHO

    // E bufpos = j+48, j in [-48,360) -> 408 floats; EB[i] = EA[i-1] (410)
    // G index  = c in [0,360) -> 360 floats;        GB[i] = GA[i-1] (362)
    __shared__ float2 sEA[204], sEB[205], sGA[180], sGB[181];
    __shared__ __align__(16) float s_red[NACC * NWAVE];   // per-phase per-wave
    __shared__ float s_R[NACC];
    float* const EAf = (float*)sEA;  float* const EBf = (float*)sEB;
    float* const GAf = (float*)sGA;  float* const GBf = (float*)sGB;

    // zero-fill band guards before first use
    if (tid < 205) {
        sEB[tid] = make_float2(0.f, 0.f);
        if (tid < 204) sEA[tid] = make_float2(0.f, 0.f);
        if (tid < 181) sGB[tid] = make_float2(0.f, 0.f);
        if (tid < 180) sGA[tid] = make_float2(0.f, 0.f);
    }

    const bool rowAct = (half < WROWS);
    const bool colAct = (half >= 1 && half < CCOLS);
    const int b = bid >> 6, h = bid & 63;
    const float* src = scores + ((size_t)(b * MAXD) * 64 + h) * WROWS;
    const size_t dstr = (size_t)64 * WROWS;
    const int d0 = sub * KD;
    const int jr = rowAct ? half : 0;
    const int jc = colAct ? half : 0;

    // ---- register weight caches (fixed across all iterations) ----
    float wcol[KD];    // e^s[d0+m][c-48+d0+m], 0 if OOB   (col band, ascending)
    float wrowR[KD];   // e^s[d0+23-m][j]                  (row band, window order)
    #pragma unroll
    for (int m = 0; m < KD; ++m) {
        wrowR[m] = __expf(src[dstr * (size_t)(d0 + 23 - m) + jr]);
        int j = jc - MAXD + d0 + m;
        bool v = colAct && ((unsigned)j < (unsigned)WROWS);
        float sv = src[dstr * (size_t)(d0 + m) + (v ? j : 0)];
        wcol[m] = v ? __expf(sv) : 0.0f;
    }

    // parity-matched band base pointers (fixed across iterations)
    const int pe = jc + d0;                 // E bufpos window start (= jb+48)
    const float2* const ep = (pe & 1) ? (sEB + ((pe + 1) >> 1)) : (sEA + (pe >> 1));
    const int qg = jr + 25 - d0;            // G window start (= gb-23)
    const float2* const gp = (qg & 1) ? (sGB + ((qg + 1) >> 1)) : (sGA + (qg >> 1));

    __syncthreads();   // B0: zeros visible

    // ---- init: Ehat0 = 1/sum(w); partial y0 = 2^(lsum/RHO + LOG_A2) ----
    {
        float a0=0,a1=0,a2=0,a3=0;
        #pragma unroll
        for (int m = 0; m < KD; m += 4) {
            a0 += wrowR[m];   a1 += wrowR[m+1];
            a2 += wrowR[m+2]; a3 += wrowR[m+3];
        }
        float s  = pair_sum((a0 + a1) + (a2 + a3));
        float ls = __builtin_amdgcn_logf(s);
        float eh = __builtin_amdgcn_exp2f(-ls);
        bool own = rowAct && (sub == 0);
        if (own) { EAf[half + MAXD] = eh; EBf[half + MAXD + 1] = eh; }
        float yv = __builtin_amdgcn_exp2f(fmaf(INVRHO, ls, LOG_A2));
        float t  = dpp_sum64(own ? yv : 0.0f);
        if ((tid & 63) == 63) s_red[0 * NWAVE + wid] = t;
        __syncthreads();
    }

    // ---- Sinkhorn iterations: 1 barrier per phase, no scalar deps ----
    float2 gv[12];
    float ehat = 0.f, den = 0.f;
    for (int it = 0; it < NITER; ++it) {
        // col phase: Ghat_c = (sum_d w * Ehat)^-TAU
        float a0=0,a1=0,a2=0,a3=0;
        #pragma unroll
        for (int u = 0; u < 12; u += 2) {
            float2 v0 = ep[u], v1 = ep[u+1];
            a0 = fmaf(wcol[2*u],   v0.x, a0);
            a1 = fmaf(wcol[2*u+1], v0.y, a1);
            a2 = fmaf(wcol[2*u+2], v1.x, a2);
            a3 = fmaf(wcol[2*u+3], v1.y, a3);
        }
        float cs  = pair_sum((a0 + a1) + (a2 + a3));
        float lcs = __builtin_amdgcn_logf(cs);
        float gh  = __builtin_amdgcn_exp2f(-TAU * lcs);
        bool ownC = colAct && (sub == 0);
        if (ownC) { GAf[half] = gh; GBf[half + 1] = gh; }
        float yv = __builtin_amdgcn_exp2f(fmaf(TIR, lcs, LOG_B2));
        float tg = dpp_sum64(ownC ? yv : 0.0f);
        if ((tid & 63) == 63) s_red[(1 + 2*it) * NWAVE + wid] = tg;
        __syncthreads();                      // Ghat + slot visible

        // row phase: Ehat_j = (sum_d w * Ghat)^-TAU  (keep window in gv)
        float b0=0,b1=0,b2=0,b3=0;
        #pragma unroll
        for (int u = 0; u < 12; u += 2) {
            gv[u] = gp[u]; gv[u+1] = gp[u+1];
            b0 = fmaf(wrowR[2*u],   gv[u].x,   b0);
            b1 = fmaf(wrowR[2*u+1], gv[u].y,   b1);
            b2 = fmaf(wrowR[2*u+2], gv[u+1].x, b2);
            b3 = fmaf(wrowR[2*u+3], gv[u+1].y, b3);
        }
        den = pair_sum((b0 + b1) + (b2 + b3));
        float lrs = __builtin_amdgcn_logf(den);
        ehat = __builtin_amdgcn_exp2f(-TAU * lrs);
        bool ownR = rowAct && (sub == 0);
        if (ownR) { EAf[half + MAXD] = ehat; EBf[half + MAXD + 1] = ehat; }
        float yf = __builtin_amdgcn_exp2f(fmaf(TIR, lrs, LOG_A2));
        float tf = dpp_sum64(ownR ? yf : 0.0f);
        if ((tid & 63) == 63) s_red[(2 + 2*it) * NWAVE + wid] = tf;
        __syncthreads();                      // Ehat + slot visible
    }

    // ---- combine per-wave partials: thread t handles phase t ----
    if (tid < NACC) {
        const float4* rp = (const float4*)(s_red + tid * NWAVE);
        float4 a = rp[0], b = rp[1], c = rp[2];
        float s = ((a.x + a.y) + (a.z + a.w))
                + (((b.x + b.y) + (b.z + b.w)) + ((c.x + c.y) + (c.z + c.w)));
        s_R[tid] = __builtin_amdgcn_logf(s);
    }
    __syncthreads();

    // ---- scalar recurrence from the 21 reduction values (uniform) ----
    float fsh   = -LOG_B2;
    float sminF = fsh - RHO * s_R[0];
    float gsh   = 0.f;
    #pragma unroll
    for (int it = 0; it < NITER; ++it) {
        float Cg = TAU * (LOG_B2 - fsh) - KAPPA * sminF;
        float sg = Cg - RHO * s_R[1 + 2*it];
        gsh = Cg + XI * sg;
        float sminG = (1.0f + XI) * sg;
        float Cf = TAU * (LOG_A2 - gsh) - KAPPA * sminG;
        float sf = Cf - RHO * s_R[2 + 2*it];
        fsh   = Cf + XI * sf;
        sminF = (1.0f + XI) * sf;
    }

    // ---- disparity from last row window (den = rs_last, num from gv) ----
    float n0 = 0.f, n1 = 0.f;
    #pragma unroll
    for (int u = 0; u < 12; ++u) {
        n0 = fmaf((float)(d0 + 23 - 2*u) * wrowR[2*u],   gv[u].x, n0);
        n1 = fmaf((float)(d0 + 22 - 2*u) * wrowR[2*u+1], gv[u].y, n1);
    }
    float num = pair_sum(n0 + n1);
    if (rowAct && sub == 0) {
        float E = __builtin_amdgcn_exp2f(fsh + gsh) * ehat;   // full 2^f_j
        float mass = fmaxf(E * den, 1e-8f);
        out[(size_t)bid * WROWS + half] = (E * num) / mass;
    }
}

extern "C" void kernel_launch(void* const* d_in, const int* in_sizes, int n_in,
                              void* d_out, int out_size, void* d_ws, size_t ws_size,
                              hipStream_t stream) {
    const float* scores = (const float*)d_in[0];
    float* out = (float*)d_out;
    ot_disp_kernel<<<128, NT, 0, stream>>>(scores, out);
}

// Round 8
// 24.558 us; speedup vs baseline: 3.8469x; 1.0039x over previous
//
#include <hip/hip_runtime.h>
#include <math.h>

// Banded unbalanced Sinkhorn OT -> disparity. One (b,h) problem per block.
// Band iteration is scalar-free: Ghat = (sum w*Ehat)^-tau, Ehat' = (sum w*Ghat)^-tau.
// Per-phase owners write raw log2 values to per-phase LDS arrays; ALL block
// reductions + the uniform-shift scalar recurrence are evaluated once at the
// end. E/G stored in parity-duplicated LDS arrays -> aligned float2 reads.
// __launch_bounds__(NT,3): 1 block/CU reality -> full VGPR budget, no spills.

#define MAXD   48
#define WROWS  312
#define CCOLS  360
#define NITER  10
#define NT     768
#define NWAVE  12
#define KD     24
#define NACC   (2 * NITER + 1)

// quad_perm [1,0,3,2]: both lanes of a pair get the pair sum
__device__ __forceinline__ float pair_sum(float x) {
    int y = __builtin_amdgcn_update_dpp(0, __float_as_int(x), 0xB1, 0xf, 0xf, true);
    return x + __int_as_float(y);
}
template <int CTRL>
__device__ __forceinline__ float dpp_add(float x, float acc) {
    int y = __builtin_amdgcn_update_dpp(0, __float_as_int(x), CTRL, 0xf, 0xf, true);
    return acc + __int_as_float(y);
}
// 64-lane sum; valid in lane 63 only.
__device__ __forceinline__ float dpp_sum64(float x) {
    x = dpp_add<0x111>(x, x);   // row_shr:1
    x = dpp_add<0x112>(x, x);   // row_shr:2
    x = dpp_add<0x114>(x, x);   // row_shr:4
    x = dpp_add<0x118>(x, x);   // row_shr:8
    x = dpp_add<0x142>(x, x);   // row_bcast:15
    x = dpp_add<0x143>(x, x);   // row_bcast:31
    return x;
}

__global__ __launch_bounds__(NT, 3)
void ot_disp_kernel(const float* __restrict__ scores, float* __restrict__ out) {
    const int bid  = blockIdx.x;     // 0..127 (= b*64 + h)
    const int tid  = threadIdx.x;
    const int half = tid >> 1;       // column c (col pass) / row j (row pass)
    const int sub  = tid & 1;
    const int wid  = tid >> 6;

    const float LOG_A2 = -8.2854022f;    // -log2(312)
    const float LOG_B2 = -8.4918531f;    // -log2(360)
    const float TAU    = 0.95f;
    const float KAPPA  = 0.025f;
    const float XI     = 0.025641026f;
    const float RHO    = 19.0f;
    const float INVRHO = 0.052631579f;
    const float TIR    = 0.05f;          // TAU/RHO

    // E bufpos = j+48, j in [-48,360) -> 408 floats; EB[i] = EA[i-1] (410)
    // G index  = c in [0,360) -> 360 floats;        GB[i] = GA[i-1] (362)
    __shared__ float2 sEA[204], sEB[205], sGA[180], sGB[181];
    __shared__ __align__(16) float s_lg[NACC][384];   // raw per-phase log2 vals
    __shared__ float s_R[NACC];
    float* const EAf = (float*)sEA;  float* const EBf = (float*)sEB;
    float* const GAf = (float*)sGA;  float* const GBf = (float*)sGB;

    // fill phase-log arrays with -1e30 (dead slots -> exp2 -> exact 0)
    {
        float4* lg4 = (float4*)&s_lg[0][0];
        #pragma unroll
        for (int i = 0; i < 3; ++i) {
            int idx = tid + i * NT;
            if (idx < NACC * 96) lg4[idx] = make_float4(-1e30f, -1e30f, -1e30f, -1e30f);
        }
    }
    // zero-fill band guards before first use
    if (tid < 205) {
        sEB[tid] = make_float2(0.f, 0.f);
        if (tid < 204) sEA[tid] = make_float2(0.f, 0.f);
        if (tid < 181) sGB[tid] = make_float2(0.f, 0.f);
        if (tid < 180) sGA[tid] = make_float2(0.f, 0.f);
    }

    const bool rowAct = (half < WROWS);
    const bool colAct = (half >= 1 && half < CCOLS);
    const int b = bid >> 6, h = bid & 63;
    const float* src = scores + ((size_t)(b * MAXD) * 64 + h) * WROWS;
    const size_t dstr = (size_t)64 * WROWS;
    const int d0 = sub * KD;
    const int jr = rowAct ? half : 0;
    const int jc = colAct ? half : 0;

    // ---- register weight caches (fixed across all iterations) ----
    float wcol[KD];    // e^s[d0+m][c-48+d0+m], 0 if OOB   (col band, ascending)
    float wrowR[KD];   // e^s[d0+23-m][j]                  (row band, window order)
    #pragma unroll
    for (int m = 0; m < KD; ++m) {
        wrowR[m] = __expf(src[dstr * (size_t)(d0 + 23 - m) + jr]);
        int j = jc - MAXD + d0 + m;
        bool v = colAct && ((unsigned)j < (unsigned)WROWS);
        float sv = src[dstr * (size_t)(d0 + m) + (v ? j : 0)];
        wcol[m] = v ? __expf(sv) : 0.0f;
    }

    // parity-matched band base pointers (fixed across iterations)
    const int pe = jc + d0;                 // E bufpos window start (= jb+48)
    const float2* const ep = (pe & 1) ? (sEB + ((pe + 1) >> 1)) : (sEA + (pe >> 1));
    const int qg = jr + 25 - d0;            // G window start (= gb-23)
    const float2* const gp = (qg & 1) ? (sGB + ((qg + 1) >> 1)) : (sGA + (qg >> 1));

    __syncthreads();   // B0: zeros + lg fill visible

    // ---- init: Ehat0 = 1/sum(w); store ls for deferred reduction ----
    {
        float a0=0,a1=0,a2=0,a3=0;
        #pragma unroll
        for (int m = 0; m < KD; m += 4) {
            a0 += wrowR[m];   a1 += wrowR[m+1];
            a2 += wrowR[m+2]; a3 += wrowR[m+3];
        }
        float s  = pair_sum((a0 + a1) + (a2 + a3));
        float ls = __builtin_amdgcn_logf(s);
        float eh = __builtin_amdgcn_exp2f(-ls);
        if (rowAct && sub == 0) {
            EAf[half + MAXD] = eh; EBf[half + MAXD + 1] = eh;
            s_lg[0][half] = ls;
        }
        __syncthreads();
    }

    // ---- Sinkhorn iterations: 1 barrier per phase, no reduction tails ----
    float2 gv[12];
    float ehat = 0.f, den = 0.f;
    for (int it = 0; it < NITER; ++it) {
        // col phase: Ghat_c = (sum_d w * Ehat)^-TAU
        float a0=0,a1=0,a2=0,a3=0;
        #pragma unroll
        for (int u = 0; u < 12; u += 2) {
            float2 v0 = ep[u], v1 = ep[u+1];
            a0 = fmaf(wcol[2*u],   v0.x, a0);
            a1 = fmaf(wcol[2*u+1], v0.y, a1);
            a2 = fmaf(wcol[2*u+2], v1.x, a2);
            a3 = fmaf(wcol[2*u+3], v1.y, a3);
        }
        float cs  = pair_sum((a0 + a1) + (a2 + a3));
        float lcs = __builtin_amdgcn_logf(cs);
        float gh  = __builtin_amdgcn_exp2f(-TAU * lcs);
        if (colAct && sub == 0) {
            GAf[half] = gh; GBf[half + 1] = gh;
            s_lg[1 + 2*it][half] = lcs;
        }
        __syncthreads();                      // Ghat + lg visible

        // row phase: Ehat_j = (sum_d w * Ghat)^-TAU  (keep window in gv)
        float b0=0,b1=0,b2=0,b3=0;
        #pragma unroll
        for (int u = 0; u < 12; u += 2) {
            gv[u] = gp[u]; gv[u+1] = gp[u+1];
            b0 = fmaf(wrowR[2*u],   gv[u].x,   b0);
            b1 = fmaf(wrowR[2*u+1], gv[u].y,   b1);
            b2 = fmaf(wrowR[2*u+2], gv[u+1].x, b2);
            b3 = fmaf(wrowR[2*u+3], gv[u+1].y, b3);
        }
        den = pair_sum((b0 + b1) + (b2 + b3));
        float lrs = __builtin_amdgcn_logf(den);
        ehat = __builtin_amdgcn_exp2f(-TAU * lrs);
        if (rowAct && sub == 0) {
            EAf[half + MAXD] = ehat; EBf[half + MAXD + 1] = ehat;
            s_lg[2 + 2*it][half] = lrs;
        }
        __syncthreads();                      // Ehat + lg visible
    }

    // ---- deferred reductions: wave w handles phases w, w+12 ----
    {
        const int lane = tid & 63;
        for (int t = wid; t < NACC; t += NWAVE) {
            const float coef = (t == 0) ? INVRHO : TIR;
            const float cst  = (t & 1)  ? LOG_B2 : LOG_A2;
            float s = 0.f;
            #pragma unroll
            for (int k = 0; k < 6; ++k)
                s += __builtin_amdgcn_exp2f(fmaf(coef, s_lg[t][lane + 64*k], cst));
            s = dpp_sum64(s);
            if (lane == 63) s_R[t] = __builtin_amdgcn_logf(s);
        }
        __syncthreads();
    }

    // ---- scalar recurrence from the 21 reduction values (uniform) ----
    float fsh   = -LOG_B2;
    float sminF = fsh - RHO * s_R[0];
    float gsh   = 0.f;
    #pragma unroll
    for (int it = 0; it < NITER; ++it) {
        float Cg = TAU * (LOG_B2 - fsh) - KAPPA * sminF;
        float sg = Cg - RHO * s_R[1 + 2*it];
        gsh = Cg + XI * sg;
        float sminG = (1.0f + XI) * sg;
        float Cf = TAU * (LOG_A2 - gsh) - KAPPA * sminG;
        float sf = Cf - RHO * s_R[2 + 2*it];
        fsh   = Cf + XI * sf;
        sminF = (1.0f + XI) * sf;
    }

    // ---- disparity from last row window (den = rs_last, num from gv) ----
    float n0 = 0.f, n1 = 0.f;
    #pragma unroll
    for (int u = 0; u < 12; ++u) {
        n0 = fmaf((float)(d0 + 23 - 2*u) * wrowR[2*u],   gv[u].x, n0);
        n1 = fmaf((float)(d0 + 22 - 2*u) * wrowR[2*u+1], gv[u].y, n1);
    }
    float num = pair_sum(n0 + n1);
    if (rowAct && sub == 0) {
        float E = __builtin_amdgcn_exp2f(fsh + gsh) * ehat;   // full 2^f_j
        float mass = fmaxf(E * den, 1e-8f);
        out[(size_t)bid * WROWS + half] = (E * num) / mass;
    }
}

extern "C" void kernel_launch(void* const* d_in, const int* in_sizes, int n_in,
                              void* d_out, int out_size, void* d_ws, size_t ws_size,
                              hipStream_t stream) {
    const float* scores = (const float*)d_in[0];
    float* out = (float*)d_out;
    ot_disp_kernel<<<128, NT, 0, stream>>>(scores, out);
}

// Round 9
// 23.277 us; speedup vs baseline: 4.0586x; 1.0550x over previous
//
#include <hip/hip_runtime.h>
#include <math.h>

// Banded unbalanced Sinkhorn OT -> disparity. One (b,h) problem per block.
// Hat-recurrence: Ghat = (sum w*Ehat)^-tau, Ehat' = (sum w*Ghat)^-tau; all
// uniform shifts deferred to a final scalar recurrence over 21 stored log2
// reduction values. E/G live in LDS as fp16 with 4 alignment replicas ->
// each thread's 24-value band window = 6 aligned ds_read_b64. Weights are
// half2 registers; band MACs via v_dot2_f32_f16 (f32 accumulate).

typedef _Float16 half1;
typedef _Float16 half2v __attribute__((ext_vector_type(2)));
typedef _Float16 half4v __attribute__((ext_vector_type(4)));

#define MAXD   48
#define WROWS  312
#define CCOLS  360
#define NITER  10
#define NT     768
#define NWAVE  12
#define KD     24
#define NACC   (2 * NITER + 1)
#define ESTR   412   // 408 positions + 3 replica pad, multiple of 4 halfs
#define GSTR   364   // 360 positions + 3 replica pad, multiple of 4 halfs

// quad_perm [1,0,3,2]: both lanes of a pair get the pair sum
__device__ __forceinline__ float pair_sum(float x) {
    int y = __builtin_amdgcn_update_dpp(0, __float_as_int(x), 0xB1, 0xf, 0xf, true);
    return x + __int_as_float(y);
}
template <int CTRL>
__device__ __forceinline__ float dpp_add(float x, float acc) {
    int y = __builtin_amdgcn_update_dpp(0, __float_as_int(x), CTRL, 0xf, 0xf, true);
    return acc + __int_as_float(y);
}
// 64-lane sum; valid in lane 63 only.
__device__ __forceinline__ float dpp_sum64(float x) {
    x = dpp_add<0x111>(x, x);   // row_shr:1
    x = dpp_add<0x112>(x, x);   // row_shr:2
    x = dpp_add<0x114>(x, x);   // row_shr:4
    x = dpp_add<0x118>(x, x);   // row_shr:8
    x = dpp_add<0x142>(x, x);   // row_bcast:15
    x = dpp_add<0x143>(x, x);   // row_bcast:31
    return x;
}

__global__ __launch_bounds__(NT, 3)
void ot_disp_kernel(const float* __restrict__ scores, float* __restrict__ out) {
    const int bid  = blockIdx.x;     // 0..127 (= b*64 + h)
    const int tid  = threadIdx.x;
    const int half = tid >> 1;       // column c (col pass) / row j (row pass)
    const int sub  = tid & 1;
    const int wid  = tid >> 6;

    const float LOG_A2 = -8.2854022f;    // -log2(312)
    const float LOG_B2 = -8.4918531f;    // -log2(360)
    const float TAU    = 0.95f;
    const float KAPPA  = 0.025f;
    const float XI     = 0.025641026f;
    const float RHO    = 19.0f;
    const float INVRHO = 0.052631579f;
    const float TIR    = 0.05f;          // TAU/RHO

    __shared__ __align__(8) half1 sE[4 * ESTR];   // replica r: E[p] at p + r
    __shared__ __align__(8) half1 sG[4 * GSTR];
    __shared__ __align__(16) float s_lg[NACC][384];
    __shared__ float s_R[NACC];

    // zero-fill E/G replicas (guards included)
    {
        unsigned* z = (unsigned*)sE;             // 1648 halfs = 824 dwords
        for (int i = tid; i < 824; i += NT) z[i] = 0u;
        unsigned* zg = (unsigned*)sG;            // 1456 halfs = 728 dwords
        for (int i = tid; i < 728; i += NT) zg[i] = 0u;
    }
    // fill phase-log arrays with -1e30 (dead slots -> exp2 -> exact 0)
    {
        float4* lg4 = (float4*)&s_lg[0][0];
        #pragma unroll
        for (int i = 0; i < 3; ++i) {
            int idx = tid + i * NT;
            if (idx < NACC * 96) lg4[idx] = make_float4(-1e30f, -1e30f, -1e30f, -1e30f);
        }
    }

    const bool rowAct = (half < WROWS);
    const bool colAct = (half >= 1 && half < CCOLS);
    const int b = bid >> 6, h = bid & 63;
    const float* src = scores + ((size_t)(b * MAXD) * 64 + h) * WROWS;
    const size_t dstr = (size_t)64 * WROWS;
    const int d0 = sub * KD;
    const int jr = rowAct ? half : 0;
    const int jc = colAct ? half : 0;

    // ---- half2 weight caches + f32 row-weight sum (for init) ----
    half2v wcolH[12];   // w[d0+m][c-48+d0+m], 0 if OOB (ascending window order)
    half2v wrowH[12];   // w[d0+23-m][j]                (ascending-c window order)
    float swr = 0.0f;
    #pragma unroll
    for (int m = 0; m < KD; ++m) {
        float wr = __expf(src[dstr * (size_t)(d0 + 23 - m) + jr]);
        swr += wr;
        wrowH[m >> 1][m & 1] = (half1)wr;
        int j = jc - MAXD + d0 + m;
        bool v = colAct && ((unsigned)j < (unsigned)WROWS);
        float wc = v ? __expf(src[dstr * (size_t)(d0 + m) + (v ? j : 0)]) : 0.0f;
        wcolH[m >> 1][m & 1] = (half1)wc;
    }

    // band window bases (fixed across iterations), 8B-aligned via replica pick
    const int pe = jc + d0;                       // E bufpos window start
    const int rE = (4 - (pe & 3)) & 3;
    const half4v* const epk = (const half4v*)(sE + rE * ESTR + pe + rE);
    const int qg = jr + 25 - d0;                  // G window start
    const int rG = (4 - (qg & 3)) & 3;
    const half4v* const gpk = (const half4v*)(sG + rG * GSTR + qg + rG);

    __syncthreads();   // B0: zeros + lg fill visible

    // ---- init: Ehat0 = 1/sum(w); store ls for deferred reduction ----
    {
        float s  = pair_sum(swr);
        float ls = __builtin_amdgcn_logf(s);
        float eh = __builtin_amdgcn_exp2f(-ls);
        if (rowAct && sub == 0) {
            half1 he = (half1)eh;
            int p = half + MAXD;
            sE[0 * ESTR + p + 0] = he;  sE[1 * ESTR + p + 1] = he;
            sE[2 * ESTR + p + 2] = he;  sE[3 * ESTR + p + 3] = he;
            s_lg[0][half] = ls;
        }
        __syncthreads();
    }

    // ---- Sinkhorn iterations: 1 barrier per phase ----
    half4v gsave[6];
    float ehat = 0.f, den = 0.f;
    for (int it = 0; it < NITER; ++it) {
        // col phase: Ghat_c = (sum_d w * Ehat)^-TAU
        float a0 = 0.f, a1 = 0.f, a2 = 0.f, a3 = 0.f;
        #pragma unroll
        for (int u = 0; u < 6; u += 2) {
            half4v v = epk[u], w = epk[u + 1];
            a0 = __builtin_amdgcn_fdot2(wcolH[2*u],   __builtin_shufflevector(v, v, 0, 1), a0, false);
            a1 = __builtin_amdgcn_fdot2(wcolH[2*u+1], __builtin_shufflevector(v, v, 2, 3), a1, false);
            a2 = __builtin_amdgcn_fdot2(wcolH[2*u+2], __builtin_shufflevector(w, w, 0, 1), a2, false);
            a3 = __builtin_amdgcn_fdot2(wcolH[2*u+3], __builtin_shufflevector(w, w, 2, 3), a3, false);
        }
        float cs  = pair_sum((a0 + a1) + (a2 + a3));
        float lcs = __builtin_amdgcn_logf(cs);
        float gh  = __builtin_amdgcn_exp2f(-TAU * lcs);
        if (colAct && sub == 0) {
            half1 hg = (half1)gh;
            sG[0 * GSTR + half + 0] = hg;  sG[1 * GSTR + half + 1] = hg;
            sG[2 * GSTR + half + 2] = hg;  sG[3 * GSTR + half + 3] = hg;
            s_lg[1 + 2*it][half] = lcs;
        }
        __syncthreads();                      // Ghat + lg visible

        // row phase: Ehat_j = (sum_d w * Ghat)^-TAU (keep window in gsave)
        float b0 = 0.f, b1 = 0.f, b2 = 0.f, b3 = 0.f;
        #pragma unroll
        for (int u = 0; u < 6; u += 2) {
            half4v v = gpk[u], w = gpk[u + 1];
            gsave[u] = v; gsave[u + 1] = w;
            b0 = __builtin_amdgcn_fdot2(wrowH[2*u],   __builtin_shufflevector(v, v, 0, 1), b0, false);
            b1 = __builtin_amdgcn_fdot2(wrowH[2*u+1], __builtin_shufflevector(v, v, 2, 3), b1, false);
            b2 = __builtin_amdgcn_fdot2(wrowH[2*u+2], __builtin_shufflevector(w, w, 0, 1), b2, false);
            b3 = __builtin_amdgcn_fdot2(wrowH[2*u+3], __builtin_shufflevector(w, w, 2, 3), b3, false);
        }
        den = pair_sum((b0 + b1) + (b2 + b3));
        float lrs = __builtin_amdgcn_logf(den);
        ehat = __builtin_amdgcn_exp2f(-TAU * lrs);
        if (rowAct && sub == 0) {
            half1 he = (half1)ehat;
            int p = half + MAXD;
            sE[0 * ESTR + p + 0] = he;  sE[1 * ESTR + p + 1] = he;
            sE[2 * ESTR + p + 2] = he;  sE[3 * ESTR + p + 3] = he;
            s_lg[2 + 2*it][half] = lrs;
        }
        __syncthreads();                      // Ehat + lg visible
    }

    // ---- deferred reductions: wave w handles phases w, w+12 ----
    {
        const int lane = tid & 63;
        for (int t = wid; t < NACC; t += NWAVE) {
            const float coef = (t == 0) ? INVRHO : TIR;
            const float cst  = (t & 1)  ? LOG_B2 : LOG_A2;
            float s = 0.f;
            #pragma unroll
            for (int k = 0; k < 6; ++k)
                s += __builtin_amdgcn_exp2f(fmaf(coef, s_lg[t][lane + 64*k], cst));
            s = dpp_sum64(s);
            if (lane == 63) s_R[t] = __builtin_amdgcn_logf(s);
        }
        __syncthreads();
    }

    // ---- scalar recurrence from the 21 reduction values (uniform) ----
    float fsh   = -LOG_B2;
    float sminF = fsh - RHO * s_R[0];
    float gsh   = 0.f;
    #pragma unroll
    for (int it = 0; it < NITER; ++it) {
        float Cg = TAU * (LOG_B2 - fsh) - KAPPA * sminF;
        float sg = Cg - RHO * s_R[1 + 2*it];
        gsh = Cg + XI * sg;
        float sminG = (1.0f + XI) * sg;
        float Cf = TAU * (LOG_A2 - gsh) - KAPPA * sminG;
        float sf = Cf - RHO * s_R[2 + 2*it];
        fsh   = Cf + XI * sf;
        sminF = (1.0f + XI) * sf;
    }

    // ---- disparity: num = sum(d * w * G) over last row window ----
    float num = 0.f;
    #pragma unroll
    for (int u = 0; u < 6; ++u) {
        #pragma unroll
        for (int t = 0; t < 4; ++t) {
            int m = 4 * u + t;                       // window offset
            float wv = (float)wrowH[m >> 1][m & 1];  // weight for d = d0+23-m
            float gv = (float)gsave[u][t];
            num = fmaf((float)(d0 + 23 - m) * wv, gv, num);
        }
    }
    num = pair_sum(num);
    if (rowAct && sub == 0) {
        float E = __builtin_amdgcn_exp2f(fsh + gsh) * ehat;   // full 2^f_j
        float mass = fmaxf(E * den, 1e-8f);
        out[(size_t)bid * WROWS + half] = (E * num) / mass;
    }
}

extern "C" void kernel_launch(void* const* d_in, const int* in_sizes, int n_in,
                              void* d_out, int out_size, void* d_ws, size_t ws_size,
                              hipStream_t stream) {
    const float* scores = (const float*)d_in[0];
    float* out = (float*)d_out;
    ot_disp_kernel<<<128, NT, 0, stream>>>(scores, out);
}